// Round 4
// baseline (354.099 us; speedup 1.0000x reference)
//
#include <hip/hip_runtime.h>

#define SCALE 0.125f

constexpr int L_ = 1024, T_ = 1024, D_ = 64, HB_ = 64;

using f32x4 = __attribute__((ext_vector_type(4))) float;
using half8 = __attribute__((ext_vector_type(8))) _Float16;
using half4 = __attribute__((ext_vector_type(4))) _Float16;

// ---------------------------------------------------------------------------
// K1: swapped QK^T (C-tile = S^T, t rows x q cols; lane owns q = w*16+l15).
// prev loads are dwordx4 (4 consecutive t), E stores dwordx2 f16 into the
// upper half of each att row (f16 needs 2KB of the 4KB f32 row). Z in regs.
// No LDS, no barriers.
// ---------------------------------------------------------------------------
__global__ __launch_bounds__(256, 4) void zpass(
    const float* __restrict__ q, const float* __restrict__ kk,
    const float* __restrict__ prev, float* __restrict__ att,
    float* __restrict__ rz) {
  const int ltile = blockIdx.x, hb = blockIdx.y;
  const int tid = threadIdx.x;
  const int w = tid >> 6, l = tid & 63, l15 = l & 15, lg = l >> 4;
  const int qrow = ltile * 64 + w * 16 + l15;

  // Q B-frag: lane holds Q[qrow][f*32 + lg*8 + e]
  half8 qb[2];
  {
    const float* qp = q + ((size_t)hb * L_ + qrow) * D_ + lg * 8;
#pragma unroll
    for (int f = 0; f < 2; ++f)
#pragma unroll
      for (int e = 0; e < 8; ++e) qb[f][e] = (_Float16)qp[f * 32 + e];
  }

  const float* prow = prev + ((size_t)hb * L_ + qrow) * (size_t)T_;
  const float* kbase = kk + (size_t)hb * T_ * D_;
  _Float16* erow =
      (_Float16*)(att + ((size_t)hb * L_ + qrow) * (size_t)T_) + T_;

  f32x4 pb[2][4];  // double-buffered prev prefetch (4 dwordx4 per chunk)
  auto load_prev = [&](int c, int buf) {
#pragma unroll
    for (int nt = 0; nt < 4; ++nt)
      pb[buf][nt] = *(const f32x4*)(prow + c * 64 + nt * 16 + lg * 4);
  };

  load_prev(0, 0);
  float zsum = 0.f;

#pragma unroll 4
  for (int c = 0; c < 16; ++c) {
    if (c < 15) load_prev(c + 1, (c + 1) & 1);
    const int t0 = c * 64;
#pragma unroll
    for (int nt = 0; nt < 4; ++nt) {
      // K A-frag: K[t0+nt*16+l15][k], k = {lg*8..+7, 32+lg*8..+7}
      const float* kp = kbase + (size_t)(t0 + nt * 16 + l15) * D_ + lg * 8;
      float4 a0 = *(const float4*)(kp);
      float4 a1 = *(const float4*)(kp + 4);
      float4 b0 = *(const float4*)(kp + 32);
      float4 b1 = *(const float4*)(kp + 36);
      half8 ka0, ka1;
      ka0[0] = (_Float16)a0.x; ka0[1] = (_Float16)a0.y;
      ka0[2] = (_Float16)a0.z; ka0[3] = (_Float16)a0.w;
      ka0[4] = (_Float16)a1.x; ka0[5] = (_Float16)a1.y;
      ka0[6] = (_Float16)a1.z; ka0[7] = (_Float16)a1.w;
      ka1[0] = (_Float16)b0.x; ka1[1] = (_Float16)b0.y;
      ka1[2] = (_Float16)b0.z; ka1[3] = (_Float16)b0.w;
      ka1[4] = (_Float16)b1.x; ka1[5] = (_Float16)b1.y;
      ka1[6] = (_Float16)b1.z; ka1[7] = (_Float16)b1.w;

      f32x4 acc = {0.f, 0.f, 0.f, 0.f};
      acc = __builtin_amdgcn_mfma_f32_16x16x32_f16(ka0, qb[0], acc, 0, 0, 0);
      acc = __builtin_amdgcn_mfma_f32_16x16x32_f16(ka1, qb[1], acc, 0, 0, 0);

      // acc[i] = S^T[t0+nt*16+lg*4+i][qrow]
      f32x4 pv = pb[c & 1][nt];
      float e0 = __expf(acc[0] * SCALE + pv[0]);
      float e1 = __expf(acc[1] * SCALE + pv[1]);
      float e2 = __expf(acc[2] * SCALE + pv[2]);
      float e3 = __expf(acc[3] * SCALE + pv[3]);
      zsum += (e0 + e1) + (e2 + e3);
      half4 ev;
      ev[0] = (_Float16)e0; ev[1] = (_Float16)e1;
      ev[2] = (_Float16)e2; ev[3] = (_Float16)e3;
      *(half4*)(erow + t0 + nt * 16 + lg * 4) = ev;
    }
  }

  // Z[qrow]: reduce over the 4 lg lanes sharing l15
  zsum += __shfl_xor(zsum, 16, 64);
  zsum += __shfl_xor(zsum, 32, 64);
  if (lg == 0) rz[(size_t)hb * L_ + qrow] = 1.0f / zsum;
}

// ---------------------------------------------------------------------------
// K2: read E (f16 A-frags, 16B loads), normalize with rz, store att f32
// directly from registers (coalesced f32x4), MFMA with LDS-staged V^T.
// In-place: att-row writes of chunk c only clobber E chunks already retired.
// ---------------------------------------------------------------------------
__global__ __launch_bounds__(256, 4) void pvpass(
    const float* __restrict__ vv, const float* __restrict__ rz,
    float* __restrict__ out, float* __restrict__ att) {
  __shared__ __align__(16) _Float16 Vt[2][64][72];  // V^T chunk [d][t]

  const int ltile = blockIdx.x, hb = blockIdx.y;
  const int tid = threadIdx.x;
  const int w = tid >> 6, l = tid & 63, l15 = l & 15, lg = l >> 4;
  const int qrow = ltile * 64 + w * 16 + l15;

  const float rzq = rz[(size_t)hb * L_ + qrow];
  float* arow = att + ((size_t)hb * L_ + qrow) * (size_t)T_;
  const _Float16* erow = (const _Float16*)arow + T_;

  const float* vbase = vv + (size_t)hb * T_ * D_;
  const int sr = tid >> 2;          // staging t-row 0..63
  const int dj = (tid & 3) * 4;     // interleaved d base (bank-conflict fix)

  float4 sv[4];
  auto stage_load = [&](int t0) {
    const float* vp = vbase + (size_t)(t0 + sr) * D_;
#pragma unroll
    for (int p = 0; p < 4; ++p) sv[p] = *(const float4*)(vp + p * 16 + dj);
  };
  auto stage_write = [&](int buf) {
#pragma unroll
    for (int p = 0; p < 4; ++p) {
      Vt[buf][p * 16 + dj + 0][sr] = (_Float16)sv[p].x;
      Vt[buf][p * 16 + dj + 1][sr] = (_Float16)sv[p].y;
      Vt[buf][p * 16 + dj + 2][sr] = (_Float16)sv[p].z;
      Vt[buf][p * 16 + dj + 3][sr] = (_Float16)sv[p].w;
    }
  };

  half8 eb[2][2];  // double-buffered E A-frags (2 k-halves)
  auto load_e = [&](int c, int buf) {
    eb[buf][0] = *(const half8*)(erow + c * 64 + lg * 8);
    eb[buf][1] = *(const half8*)(erow + c * 64 + 32 + lg * 8);
  };

  stage_load(0);
  stage_write(0);
  load_e(0, 0);

  f32x4 oacc[4];
#pragma unroll
  for (int nd = 0; nd < 4; ++nd) oacc[nd] = (f32x4){0.f, 0.f, 0.f, 0.f};

#pragma unroll
  for (int c = 0; c < 16; ++c) {
    __syncthreads();                       // Vt[c&1] staged for all waves
    const int buf = c & 1;
    if (c < 15) {
      stage_load((c + 1) * 64);            // issue early (T14)
      load_e(c + 1, (c + 1) & 1);          // never reads clobbered bytes
    }

    // normalize + att store (direct from regs) + build A-frags
    half8 af[2];
#pragma unroll
    for (int ks = 0; ks < 2; ++ks) {
      half8 ef = eb[buf][ks];
      f32x4 s0, s1;
#pragma unroll
      for (int e = 0; e < 4; ++e) {
        float v0 = (float)ef[e] * rzq;
        float v1 = (float)ef[4 + e] * rzq;
        s0[e] = v0; s1[e] = v1;
        af[ks][e] = (_Float16)v0;
        af[ks][4 + e] = (_Float16)v1;
      }
      *(f32x4*)(arow + c * 64 + ks * 32 + lg * 8) = s0;
      *(f32x4*)(arow + c * 64 + ks * 32 + lg * 8 + 4) = s1;
    }

    // PV: O += A * V   (A rows = q, B rows = d from Vt)
#pragma unroll
    for (int ks = 0; ks < 2; ++ks)
#pragma unroll
      for (int nd = 0; nd < 4; ++nd) {
        half8 vb = *(const half8*)&Vt[buf][nd * 16 + l15][ks * 32 + lg * 8];
        oacc[nd] =
            __builtin_amdgcn_mfma_f32_16x16x32_f16(af[ks], vb, oacc[nd], 0, 0, 0);
      }

    if (c < 15) stage_write(buf ^ 1);      // write late, before next barrier
  }

  // epilogue: O already normalized. oacc[nd][i] = O[w*16+lg*4+i][nd*16+l15]
  float* outw =
      out + ((size_t)hb * L_ + ltile * 64 + w * 16 + lg * 4) * (size_t)D_;
#pragma unroll
  for (int nd = 0; nd < 4; ++nd)
#pragma unroll
    for (int i = 0; i < 4; ++i)
      outw[(size_t)i * D_ + nd * 16 + l15] = oacc[nd][i];
}

extern "C" void kernel_launch(void* const* d_in, const int* in_sizes, int n_in,
                              void* d_out, int out_size, void* d_ws,
                              size_t ws_size, hipStream_t stream) {
  const float* q    = (const float*)d_in[0];  // (H,B,L,D)
  const float* k    = (const float*)d_in[1];  // (H,B,T,D)
  const float* v    = (const float*)d_in[2];  // (H,B,T,D)
  const float* prev = (const float*)d_in[3];  // (H,B,L,T)

  float* out = (float*)d_out;                 // (H,B,L,D)
  float* att = out + (size_t)HB_ * L_ * D_;   // (H,B,L,T)
  float* rz  = (float*)d_ws;                  // HB*L floats (256 KB)

  dim3 grid(L_ / 64, HB_);
  zpass<<<grid, 256, 0, stream>>>(q, k, prev, att, rz);
  pvpass<<<grid, 256, 0, stream>>>(v, rz, out, att);
}

// Round 5
// 254.822 us; speedup vs baseline: 1.3896x; 1.3896x over previous
//
#include <hip/hip_runtime.h>

#define SCALE 0.125f

constexpr int L_ = 1024, T_ = 1024, D_ = 64, HB_ = 64;

using f32x4 = __attribute__((ext_vector_type(4))) float;
using half8 = __attribute__((ext_vector_type(8))) _Float16;
using half4 = __attribute__((ext_vector_type(4))) _Float16;

// ---------------------------------------------------------------------------
// K1 (zpass): swapped QK^T (C = S^T tile; lane's column = its q-row).
// K staged to LDS as f16 (cooperative, double-buffered, load-early/write-late).
// prev loads dwordx4 with depth-2 prefetch. E = exp(score) stored f16
// (dwordx2) into the upper 2KB of each att row. Z accumulated in regs.
// ---------------------------------------------------------------------------
__global__ __launch_bounds__(256, 4) void zpass(
    const float* __restrict__ q, const float* __restrict__ kk,
    const float* __restrict__ prev, float* __restrict__ att,
    float* __restrict__ rz) {
  __shared__ __align__(16) _Float16 Ks[2][64][72];

  const int ltile = blockIdx.x, hb = blockIdx.y;
  const int tid = threadIdx.x;
  const int w = tid >> 6, l = tid & 63, l15 = l & 15, lg = l >> 4;
  const int qrow = ltile * 64 + w * 16 + l15;

  // Q B-frag: lane holds Q[qrow][f*32 + lg*8 + e]
  half8 qb[2];
  {
    const float* qp = q + ((size_t)hb * L_ + qrow) * D_ + lg * 8;
#pragma unroll
    for (int f = 0; f < 2; ++f)
#pragma unroll
      for (int e = 0; e < 8; ++e) qb[f][e] = (_Float16)qp[f * 32 + e];
  }

  const float* prow = prev + ((size_t)hb * L_ + qrow) * (size_t)T_;
  const float* kbase = kk + (size_t)hb * T_ * D_;
  _Float16* erow =
      (_Float16*)(att + ((size_t)hb * L_ + qrow) * (size_t)T_) + T_;

  // cooperative K staging: 64 rows x 64 f32 per chunk; thread loads 4 float4
  const int sr = tid >> 2;          // t-row 0..63
  const int sc = (tid & 3) * 16;    // col base 0,16,32,48

  float4 kreg[4];
  auto kload = [&](int t0) {
    const float* kp = kbase + (size_t)(t0 + sr) * D_ + sc;
#pragma unroll
    for (int p = 0; p < 4; ++p) kreg[p] = *(const float4*)(kp + p * 4);
  };
  auto kwrite = [&](int buf) {
#pragma unroll
    for (int p = 0; p < 4; ++p) {
      Ks[buf][sr][sc + p * 4 + 0] = (_Float16)kreg[p].x;
      Ks[buf][sr][sc + p * 4 + 1] = (_Float16)kreg[p].y;
      Ks[buf][sr][sc + p * 4 + 2] = (_Float16)kreg[p].z;
      Ks[buf][sr][sc + p * 4 + 3] = (_Float16)kreg[p].w;
    }
  };

  // prev prefetch, depth 2 (3 rotating buffers, statically indexed)
  f32x4 pb[3][4];
  auto pload = [&](int c, int s) {
#pragma unroll
    for (int nt = 0; nt < 4; ++nt)
      pb[s][nt] = *(const f32x4*)(prow + c * 64 + nt * 16 + lg * 4);
  };

  kload(0);
  kwrite(0);
  pload(0, 0);
  pload(1, 1);

  float zsum = 0.f;

#pragma unroll
  for (int c = 0; c < 16; ++c) {
    const int cur = c & 1;
    if (c < 15) kload((c + 1) * 64);   // issue next K tile early (T14)
    if (c < 14) pload(c + 2, (c + 2) % 3);
    __syncthreads();                   // Ks[cur] (written last iter) ready

#pragma unroll
    for (int nt = 0; nt < 4; ++nt) {
      // A-frag: K[t0+nt*16+l15][{lg*8..+7, 32+lg*8..+7}] from LDS
      half8 ka0 = *(const half8*)&Ks[cur][nt * 16 + l15][lg * 8];
      half8 ka1 = *(const half8*)&Ks[cur][nt * 16 + l15][32 + lg * 8];
      f32x4 acc = {0.f, 0.f, 0.f, 0.f};
      acc = __builtin_amdgcn_mfma_f32_16x16x32_f16(ka0, qb[0], acc, 0, 0, 0);
      acc = __builtin_amdgcn_mfma_f32_16x16x32_f16(ka1, qb[1], acc, 0, 0, 0);

      // acc[i] = S^T[c*64 + nt*16 + lg*4 + i][qrow]
      f32x4 pv = pb[c % 3][nt];
      float e0 = __expf(acc[0] * SCALE + pv[0]);
      float e1 = __expf(acc[1] * SCALE + pv[1]);
      float e2 = __expf(acc[2] * SCALE + pv[2]);
      float e3 = __expf(acc[3] * SCALE + pv[3]);
      zsum += (e0 + e1) + (e2 + e3);
      half4 ev;
      ev[0] = (_Float16)e0; ev[1] = (_Float16)e1;
      ev[2] = (_Float16)e2; ev[3] = (_Float16)e3;
      *(half4*)(erow + c * 64 + nt * 16 + lg * 4) = ev;
    }

    if (c < 15) kwrite(cur ^ 1);       // write late; next barrier guards it
  }

  // Z[qrow]: reduce over the 4 lg lanes sharing l15
  zsum += __shfl_xor(zsum, 16, 64);
  zsum += __shfl_xor(zsum, 32, 64);
  if (lg == 0) rz[(size_t)hb * L_ + qrow] = 1.0f / zsum;
}

// ---------------------------------------------------------------------------
// K2 (pvpass): read E (f16 A-frags, 16B loads), normalize with rz, store att
// f32 directly from registers (coalesced f32x4), MFMA with LDS-staged V^T.
// In-place: att-row writes of chunk c only clobber E chunks already retired.
// ---------------------------------------------------------------------------
__global__ __launch_bounds__(256, 4) void pvpass(
    const float* __restrict__ vv, const float* __restrict__ rz,
    float* __restrict__ out, float* __restrict__ att) {
  __shared__ __align__(16) _Float16 Vt[2][64][72];  // V^T chunk [d][t]

  const int ltile = blockIdx.x, hb = blockIdx.y;
  const int tid = threadIdx.x;
  const int w = tid >> 6, l = tid & 63, l15 = l & 15, lg = l >> 4;
  const int qrow = ltile * 64 + w * 16 + l15;

  const float rzq = rz[(size_t)hb * L_ + qrow];
  float* arow = att + ((size_t)hb * L_ + qrow) * (size_t)T_;
  const _Float16* erow = (const _Float16*)arow + T_;

  const float* vbase = vv + (size_t)hb * T_ * D_;
  const int sr = tid >> 2;          // staging t-row 0..63
  const int dj = (tid & 3) * 4;     // interleaved d base

  float4 sv[4];
  auto stage_load = [&](int t0) {
    const float* vp = vbase + (size_t)(t0 + sr) * D_;
#pragma unroll
    for (int p = 0; p < 4; ++p) sv[p] = *(const float4*)(vp + p * 16 + dj);
  };
  auto stage_write = [&](int buf) {
#pragma unroll
    for (int p = 0; p < 4; ++p) {
      Vt[buf][p * 16 + dj + 0][sr] = (_Float16)sv[p].x;
      Vt[buf][p * 16 + dj + 1][sr] = (_Float16)sv[p].y;
      Vt[buf][p * 16 + dj + 2][sr] = (_Float16)sv[p].z;
      Vt[buf][p * 16 + dj + 3][sr] = (_Float16)sv[p].w;
    }
  };

  half8 eb[2][2];  // double-buffered E A-frags (2 k-halves)
  auto load_e = [&](int c, int buf) {
    eb[buf][0] = *(const half8*)(erow + c * 64 + lg * 8);
    eb[buf][1] = *(const half8*)(erow + c * 64 + 32 + lg * 8);
  };

  stage_load(0);
  stage_write(0);
  load_e(0, 0);

  f32x4 oacc[4];
#pragma unroll
  for (int nd = 0; nd < 4; ++nd) oacc[nd] = (f32x4){0.f, 0.f, 0.f, 0.f};

#pragma unroll
  for (int c = 0; c < 16; ++c) {
    __syncthreads();                       // Vt[c&1] staged for all waves
    const int buf = c & 1;
    if (c < 15) {
      stage_load((c + 1) * 64);            // issue early (T14)
      load_e(c + 1, (c + 1) & 1);          // never reads clobbered bytes
    }

    // normalize + att store (direct from regs) + build A-frags
    half8 af[2];
#pragma unroll
    for (int ks = 0; ks < 2; ++ks) {
      half8 ef = eb[buf][ks];
      f32x4 s0, s1;
#pragma unroll
      for (int e = 0; e < 4; ++e) {
        float v0 = (float)ef[e] * rzq;
        float v1 = (float)ef[4 + e] * rzq;
        s0[e] = v0; s1[e] = v1;
        af[ks][e] = (_Float16)v0;
        af[ks][4 + e] = (_Float16)v1;
      }
      *(f32x4*)(arow + c * 64 + ks * 32 + lg * 8) = s0;
      *(f32x4*)(arow + c * 64 + ks * 32 + lg * 8 + 4) = s1;
    }

    // PV: O += A * V   (A rows = q, B rows = d from Vt)
#pragma unroll
    for (int ks = 0; ks < 2; ++ks)
#pragma unroll
      for (int nd = 0; nd < 4; ++nd) {
        half8 vb = *(const half8*)&Vt[buf][nd * 16 + l15][ks * 32 + lg * 8];
        oacc[nd] =
            __builtin_amdgcn_mfma_f32_16x16x32_f16(af[ks], vb, oacc[nd], 0, 0, 0);
      }

    if (c < 15) stage_write(buf ^ 1);      // write late, before next barrier
  }

  // epilogue: oacc[nd][i] = O[w*16+lg*4+i][nd*16+l15]
  float* outw =
      out + ((size_t)hb * L_ + ltile * 64 + w * 16 + lg * 4) * (size_t)D_;
#pragma unroll
  for (int nd = 0; nd < 4; ++nd)
#pragma unroll
    for (int i = 0; i < 4; ++i)
      outw[(size_t)i * D_ + nd * 16 + l15] = oacc[nd][i];
}

extern "C" void kernel_launch(void* const* d_in, const int* in_sizes, int n_in,
                              void* d_out, int out_size, void* d_ws,
                              size_t ws_size, hipStream_t stream) {
  const float* q    = (const float*)d_in[0];  // (H,B,L,D)
  const float* k    = (const float*)d_in[1];  // (H,B,T,D)
  const float* v    = (const float*)d_in[2];  // (H,B,T,D)
  const float* prev = (const float*)d_in[3];  // (H,B,L,T)

  float* out = (float*)d_out;                 // (H,B,L,D)
  float* att = out + (size_t)HB_ * L_ * D_;   // (H,B,L,T)
  float* rz  = (float*)d_ws;                  // HB*L floats (256 KB)

  dim3 grid(L_ / 64, HB_);
  zpass<<<grid, 256, 0, stream>>>(q, k, prev, att, rz);
  pvpass<<<grid, 256, 0, stream>>>(v, rz, out, att);
}